// Round 10
// baseline (62.024 us; speedup 1.0000x reference)
//
#include <hip/hip_runtime.h>

#define NB 4
#define NV 4096
#define NF 8192
#define NP 6
#define NE 2048
#define NPP (NB * NP)              // 24 (b,p) pairs
#define CHAM_BLKS (NPP * 32 * 2)   // 1536: 32 chunks x 2 edge-halves per pp

__device__ __forceinline__ float readlane_f(float v, int l) {
    return __int_as_float(__builtin_amdgcn_readlane(__float_as_int(v), l));
}

// ---------------------------------------------------------------------------
// Chamfer kernel, 1536 blocks = 6 blocks/CU x 4 waves = 24 waves/CU (vs 12
// before). Each block: one 128-point chunk x ONE HALF (1024) of the edges.
// 16 edges/lane -> 48-reg table; launch_bounds(256,8) forces VGPR<=64 so all
// 24 waves/CU are resident (m69: <=64 VGPR band -> 8 waves/SIMD cap).
// Stores per-point (min over its 1024 edges) + x^2 to ws[h][pp][v].
// min(a+c, b+c) == min(a,b)+c exactly, so adding x^2 per-half pre-combine
// is bit-identical to adding it after the global min.
// ---------------------------------------------------------------------------
__global__ __launch_bounds__(256, 8) void cham_kernel(
    const float* __restrict__ xs,
    const float* __restrict__ pm,
    const float* __restrict__ em,
    float* __restrict__ ws)
{
    const int bid   = blockIdx.x;
    const int tid   = threadIdx.x;
    const int lane  = tid & 63;
    const int w     = tid >> 6;
    const int h     = bid & 1;          // edge half
    const int cb    = bid >> 1;
    const int chunk = cb & 31;
    const int pp    = cb >> 5;          // b*NP + p
    const int p     = pp % NP;
    const int b     = pp / NP;

    // Per-lane point projection (lanes 32-63 duplicate 0-31).
    float vX, vY, x2v;
    {
        int v = chunk * 128 + w * 32 + (lane & 31);
        const float* x3 = xs + (size_t)(b * NV + v) * 3;
        float x = x3[0], y = x3[1], z = x3[2];
        const float* M = pm + p * 12;                 // uniform -> s_load
        float px = fmaf(M[0], x, fmaf(M[1], y, fmaf(M[2],  z, M[3])));
        float py = fmaf(M[4], x, fmaf(M[5], y, fmaf(M[6],  z, M[7])));
        float pz = fmaf(M[8], x, fmaf(M[9], y, fmaf(M[10], z, M[11])));
        float inv = 1.0f / pz;
        vX = px * inv;
        vY = py * inv;
        x2v = fmaf(vX, vX, vY * vY);
    }

    // Edge half-table: 16 edges/lane (48 VGPRs).
    const float4* em4 = (const float4*)em + (size_t)pp * (NE / 2) + h * (NE / 4);
    float ax[16], ay[16], cc[16];
#pragma unroll
    for (int k = 0; k < 8; ++k) {
        float4 e = em4[k * 64 + lane];
        ax[2 * k]     = -2.0f * e.x;
        ay[2 * k]     = -2.0f * e.y;
        cc[2 * k]     = fmaf(e.x, e.x, e.y * e.y);
        ax[2 * k + 1] = -2.0f * e.z;
        ay[2 * k + 1] = -2.0f * e.w;
        cc[2 * k + 1] = fmaf(e.z, e.z, e.w * e.w);
    }

    float* wsb = ws + ((size_t)(h * NPP + pp)) * NV + chunk * 128 + w * 32;

    // 8 batches of 4 points; butterfly mins 4 chains interleaved.
#pragma unroll 2
    for (int qb = 0; qb < 8; ++qb) {
        float mm[4];
#pragma unroll
        for (int q = 0; q < 4; ++q) {
            const int qq = qb * 4 + q;
            float X = readlane_f(vX, qq);   // SGPR broadcast
            float Y = readlane_f(vY, qq);

            float d0 = fmaf(ay[0], Y, fmaf(ax[0], X, cc[0]));
            float d1 = fmaf(ay[1], Y, fmaf(ax[1], X, cc[1]));
            float d2 = fmaf(ay[2], Y, fmaf(ax[2], X, cc[2]));
            float d3 = fmaf(ay[3], Y, fmaf(ax[3], X, cc[3]));
            float d4 = fmaf(ay[4], Y, fmaf(ax[4], X, cc[4]));
            float d5 = fmaf(ay[5], Y, fmaf(ax[5], X, cc[5]));
            float d6 = fmaf(ay[6], Y, fmaf(ax[6], X, cc[6]));
            float d7 = fmaf(ay[7], Y, fmaf(ax[7], X, cc[7]));
            float m0 = fminf(d0, d1);
            float m1 = fminf(d2, d3);
            float m2 = fminf(d4, d5);
            float m3 = fminf(d6, d7);
            d0 = fmaf(ay[8],  Y, fmaf(ax[8],  X, cc[8]));
            d1 = fmaf(ay[9],  Y, fmaf(ax[9],  X, cc[9]));
            d2 = fmaf(ay[10], Y, fmaf(ax[10], X, cc[10]));
            d3 = fmaf(ay[11], Y, fmaf(ax[11], X, cc[11]));
            d4 = fmaf(ay[12], Y, fmaf(ax[12], X, cc[12]));
            d5 = fmaf(ay[13], Y, fmaf(ax[13], X, cc[13]));
            d6 = fmaf(ay[14], Y, fmaf(ax[14], X, cc[14]));
            d7 = fmaf(ay[15], Y, fmaf(ax[15], X, cc[15]));
            m0 = fminf(fminf(m0, d0), d1);   // v_min3_f32
            m1 = fminf(fminf(m1, d2), d3);
            m2 = fminf(fminf(m2, d4), d5);
            m3 = fminf(fminf(m3, d6), d7);
            mm[q] = fminf(fminf(m0, m1), fminf(m2, m3));
        }

#pragma unroll
        for (int off = 1; off < 64; off <<= 1) {
#pragma unroll
            for (int q = 0; q < 4; ++q)
                mm[q] = fminf(mm[q], __shfl_xor(mm[q], off));
        }

        if (lane == 0) {
            wsb[qb * 4 + 0] = mm[0] + readlane_f(x2v, qb * 4 + 0);
            wsb[qb * 4 + 1] = mm[1] + readlane_f(x2v, qb * 4 + 1);
            wsb[qb * 4 + 2] = mm[2] + readlane_f(x2v, qb * 4 + 2);
            wsb[qb * 4 + 3] = mm[3] + readlane_f(x2v, qb * 4 + 3);
        }
    }
}

// ---------------------------------------------------------------------------
// Finalize: 4 blocks (one per batch). Min-combine the two edge halves and
// sum -> chamfer[b]; gather faces -> vol_error[b]. Fixed-order, no atomics.
// ---------------------------------------------------------------------------
__global__ __launch_bounds__(256) void finalize_kernel(
    const float* __restrict__ xs,
    const int*   __restrict__ faces,
    const float* __restrict__ tv,
    const float* __restrict__ ws,
    float* __restrict__ out)
{
    const int b   = blockIdx.x;
    const int tid = threadIdx.x;

    float acc = 0.0f;
    for (int pp2 = 0; pp2 < NP; ++pp2) {
        const float* h0 = ws + (size_t)(b * NP + pp2) * NV;
        const float* h1 = ws + (size_t)(NPP + b * NP + pp2) * NV;
#pragma unroll 4
        for (int i = tid; i < NV; i += 256)
            acc += fminf(h0[i], h1[i]);
    }

    float vol = 0.0f;
    for (int f = tid; f < NF; f += 256) {
        const int* fp = faces + (size_t)(b * NF + f) * 3;
        int i0 = fp[0], i1 = fp[1], i2 = fp[2];
        const float* p0 = xs + (size_t)(b * NV + i0) * 3;
        const float* p1 = xs + (size_t)(b * NV + i1) * 3;
        const float* p2 = xs + (size_t)(b * NV + i2) * 3;
        float a0 = p0[0], a1 = p0[1], a2 = p0[2];
        float b0 = p1[0], b1 = p1[1], b2 = p1[2];
        float c0 = p2[0], c1 = p2[1], c2 = p2[2];
        float crx = a1 * b2 - a2 * b1;
        float cry = a2 * b0 - a0 * b2;
        float crz = a0 * b1 - a1 * b0;
        vol += (crx * c0 + cry * c1 + crz * c2) * (1.0f / 6.0f);
    }

    __shared__ float ra[256], rv[256];
    ra[tid] = acc;
    rv[tid] = vol;
    __syncthreads();
    for (int st = 128; st > 0; st >>= 1) {
        if (tid < st) { ra[tid] += ra[tid + st]; rv[tid] += rv[tid + st]; }
        __syncthreads();
    }
    if (tid == 0) {
        out[b] = ra[0] * (1.0f / (NP * NV));
        float d = fabsf(rv[0]) - tv[b];
        out[4 + b] = d * d;
    }
}

// ---------------------------------------------------------------------------
extern "C" void kernel_launch(void* const* d_in, const int* in_sizes, int n_in,
                              void* d_out, int out_size, void* d_ws, size_t ws_size,
                              hipStream_t stream) {
    const float* xs    = (const float*)d_in[0];
    const float* pm    = (const float*)d_in[1];
    const float* em    = (const float*)d_in[2];
    const int*   faces = (const int*)d_in[3];
    const float* tv    = (const float*)d_in[4];
    float* out = (float*)d_out;
    float* ws  = (float*)d_ws;   // 2 * 24 * 4096 floats = 786 KB of per-point mins

    cham_kernel<<<CHAM_BLKS, 256, 0, stream>>>(xs, pm, em, ws);
    finalize_kernel<<<NB, 256, 0, stream>>>(xs, faces, tv, ws, out);
}

// Round 11
// 27.115 us; speedup vs baseline: 2.2875x; 2.2875x over previous
//
#include <hip/hip_runtime.h>

#define NB 4
#define NV 4096
#define NF 8192
#define NP 6
#define NE 2048

#define NBLK 768          // exactly 3 blocks/CU x 256 CU -> one execution round
#define BPB  (NBLK / NB)  // 192 vol slices per batch

typedef float float2v __attribute__((ext_vector_type(2)));

// packed 2x fp32 FMA (VOP3P, exact IEEE fp32 per half) — halves the FMA
// instruction count of the distance kernel vs scalar v_fma_f32.
__device__ __forceinline__ float2v pk_fma(float2v a, float2v b, float2v c) {
    float2v d;
    asm("v_pk_fma_f32 %0, %1, %2, %3" : "=v"(d) : "v"(a), "v"(b), "v"(c));
    return d;
}

// ---------------------------------------------------------------------------
// Fused kernel (R6 structure, pk_fma inner loop). 768 blocks. Per block:
//   * volume slice (~43 faces)                 -> ws[NBLK + bid]
//   * chamfer chunk: 128 points x 2048 edges   -> ws[bid]
// Edges in registers as float2 pairs (16 pairs/lane x {ax,ay,cc}).
// Per 2 edges: 2 pk_fma + (min3-amortized) vs 4 fma before.
// ---------------------------------------------------------------------------
__global__ __launch_bounds__(256, 3) void fused_kernel(
    const float* __restrict__ xs,
    const float* __restrict__ pm,
    const float* __restrict__ em,
    const int*   __restrict__ faces,
    float* __restrict__ ws)
{
    __shared__ float2 sxy[128];
    __shared__ float  redv[256];
    __shared__ float  redc[4];

    const int bid  = blockIdx.x;
    const int tid  = threadIdx.x;
    const int lane = tid & 63;
    const int w    = tid >> 6;

    // ---------------- volume slice (regs die before edge table loads) ------
    {
        const int vb   = bid / BPB;
        const int j    = bid % BPB;
        const int fs   = (j * NF) / BPB;
        const int fcnt = (((j + 1) * NF) / BPB) - fs;   // 42 or 43
        float fvol = 0.0f;
        if (tid < fcnt) {
            const int* fp = faces + (size_t)(vb * NF + fs + tid) * 3;
            int i0 = fp[0], i1 = fp[1], i2 = fp[2];
            const float* p0 = xs + (size_t)(vb * NV + i0) * 3;
            const float* p1 = xs + (size_t)(vb * NV + i1) * 3;
            const float* p2 = xs + (size_t)(vb * NV + i2) * 3;
            float a0 = p0[0], a1 = p0[1], a2 = p0[2];
            float b0 = p1[0], b1 = p1[1], b2 = p1[2];
            float c0 = p2[0], c1 = p2[1], c2 = p2[2];
            float crx = a1 * b2 - a2 * b1;
            float cry = a2 * b0 - a0 * b2;
            float crz = a0 * b1 - a1 * b0;
            fvol = (crx * c0 + cry * c1 + crz * c2) * (1.0f / 6.0f);
        }
        redv[tid] = fvol;
    }

    // ---------------- chamfer setup ----------------------------------------
    const int chunk = bid & 31;
    const int pp    = bid >> 5;            // b*NP + p
    const int p     = pp % NP;
    const int b     = pp / NP;

    // Project this chunk's 128 points into LDS.
    if (tid < 128) {
        int v = chunk * 128 + tid;
        const float* x3 = xs + (size_t)(b * NV + v) * 3;
        float x = x3[0], y = x3[1], z = x3[2];
        const float* M = pm + p * 12;                  // uniform -> s_load
        float px = fmaf(M[0], x, fmaf(M[1], y, fmaf(M[2],  z, M[3])));
        float py = fmaf(M[4], x, fmaf(M[5], y, fmaf(M[6],  z, M[7])));
        float pz = fmaf(M[8], x, fmaf(M[9], y, fmaf(M[10], z, M[11])));
        float inv = 1.0f / pz;
        sxy[tid] = make_float2(px * inv, py * inv);
    }

    // Edge table into registers: 16 edge-PAIRS per lane (96 VGPRs total).
    const float4* em4 = (const float4*)em + (size_t)pp * (NE / 2);
    float2v axp[16], ayp[16], ccp[16];
#pragma unroll
    for (int k = 0; k < 16; ++k) {
        float4 e = em4[k * 64 + lane];
        axp[k] = (float2v){-2.0f * e.x, -2.0f * e.z};
        ayp[k] = (float2v){-2.0f * e.y, -2.0f * e.w};
        ccp[k] = (float2v){fmaf(e.x, e.x, e.y * e.y),
                           fmaf(e.z, e.z, e.w * e.w)};
    }
    __syncthreads();

    // ---------------- chamfer inner loop: batches of 8 points --------------
    float wsum = 0.0f;
    for (int qb = 0; qb < 32; qb += 8) {
        float mm[8];
#pragma unroll
        for (int q = 0; q < 8; ++q) {
            float2 pt = sxy[w * 32 + qb + q];   // uniform LDS broadcast
            float X = pt.x, Y = pt.y;
            float2v XX = {X, X};
            float2v YY = {Y, Y};

            float2v t0 = pk_fma(ayp[0], YY, pk_fma(axp[0], XX, ccp[0]));
            float2v t1 = pk_fma(ayp[1], YY, pk_fma(axp[1], XX, ccp[1]));
            float2v t2 = pk_fma(ayp[2], YY, pk_fma(axp[2], XX, ccp[2]));
            float2v t3 = pk_fma(ayp[3], YY, pk_fma(axp[3], XX, ccp[3]));
            float m0 = fminf(t0.x, t0.y);
            float m1 = fminf(t1.x, t1.y);
            float m2 = fminf(t2.x, t2.y);
            float m3 = fminf(t3.x, t3.y);
#pragma unroll
            for (int g = 1; g < 4; ++g) {
                t0 = pk_fma(ayp[4 * g + 0], YY, pk_fma(axp[4 * g + 0], XX, ccp[4 * g + 0]));
                t1 = pk_fma(ayp[4 * g + 1], YY, pk_fma(axp[4 * g + 1], XX, ccp[4 * g + 1]));
                t2 = pk_fma(ayp[4 * g + 2], YY, pk_fma(axp[4 * g + 2], XX, ccp[4 * g + 2]));
                t3 = pk_fma(ayp[4 * g + 3], YY, pk_fma(axp[4 * g + 3], XX, ccp[4 * g + 3]));
                m0 = fminf(fminf(m0, t0.x), t0.y);   // v_min3_f32
                m1 = fminf(fminf(m1, t1.x), t1.y);
                m2 = fminf(fminf(m2, t2.x), t2.y);
                m3 = fminf(fminf(m3, t3.x), t3.y);
            }
            mm[q] = fminf(fminf(m0, m1), fminf(m2, m3));
            wsum += fmaf(X, X, Y * Y);      // x^2 term, added outside the min
        }

        // 8 interleaved 64-lane butterfly mins (pipelined DS chains)
#pragma unroll
        for (int off = 1; off < 64; off <<= 1) {
#pragma unroll
            for (int q = 0; q < 8; ++q)
                mm[q] = fminf(mm[q], __shfl_xor(mm[q], off));
        }
        wsum += ((mm[0] + mm[1]) + (mm[2] + mm[3])) +
                ((mm[4] + mm[5]) + (mm[6] + mm[7]));
    }

    // ---------------- block reductions -------------------------------------
    if (lane == 0) redc[w] = wsum;          // all lanes hold identical wsum
    __syncthreads();
    for (int st = 128; st > 0; st >>= 1) {
        if (tid < st) redv[tid] += redv[tid + st];
        __syncthreads();
    }
    if (tid == 0) {
        ws[bid]        = (redc[0] + redc[1]) + (redc[2] + redc[3]);
        ws[NBLK + bid] = redv[0];
    }
}

// ---------------------------------------------------------------------------
// Finalize: 1 block, 256 threads; wave b handles batch b. Deterministic.
// ---------------------------------------------------------------------------
__global__ __launch_bounds__(256) void finalize_kernel(
    const float* __restrict__ ws,
    const float* __restrict__ tv,
    float* __restrict__ out)
{
    const int tid  = threadIdx.x;
    const int b    = tid >> 6;
    const int lane = tid & 63;

    const float* cp = ws + b * BPB + lane * 3;            // 192 chamfer partials
    const float* vp = ws + NBLK + b * BPB + lane * 3;     // 192 vol partials
    float cs = cp[0] + cp[1] + cp[2];
    float vs = vp[0] + vp[1] + vp[2];
#pragma unroll
    for (int off = 1; off < 64; off <<= 1) {
        cs += __shfl_xor(cs, off);
        vs += __shfl_xor(vs, off);
    }
    if (lane == 0) {
        out[b] = cs * (1.0f / (NP * NV));
        float d = fabsf(vs) - tv[b];
        out[4 + b] = d * d;
    }
}

// ---------------------------------------------------------------------------
extern "C" void kernel_launch(void* const* d_in, const int* in_sizes, int n_in,
                              void* d_out, int out_size, void* d_ws, size_t ws_size,
                              hipStream_t stream) {
    const float* xs    = (const float*)d_in[0];
    const float* pm    = (const float*)d_in[1];
    const float* em    = (const float*)d_in[2];
    const int*   faces = (const int*)d_in[3];
    const float* tv    = (const float*)d_in[4];
    float* out = (float*)d_out;
    float* ws  = (float*)d_ws;            // 1536 floats of partials

    fused_kernel<<<NBLK, 256, 0, stream>>>(xs, pm, em, faces, ws);
    finalize_kernel<<<1, 256, 0, stream>>>(ws, tv, out);
}

// Round 13
// 23.932 us; speedup vs baseline: 2.5916x; 1.1330x over previous
//
#include <hip/hip_runtime.h>

#define NB 4
#define NV 4096
#define NF 8192
#define NP 6
#define NE 2048

#define NBLK 768          // exactly 3 blocks/CU x 256 CU -> one execution round
#define BPB  (NBLK / NB)  // 192 vol slices per batch

__device__ __forceinline__ float readlane_f(float v, int l) {
    return __int_as_float(__builtin_amdgcn_readlane(__float_as_int(v), l));
}

// ---------------------------------------------------------------------------
// Fused kernel, 768 blocks (R6 macro-structure). Per block:
//   * volume slice (~43 faces)                 -> ws[NBLK + bid]
//   * chamfer chunk: 128 points x 2048 edges   -> ws[bid]
// DS-diet version: points per-lane + v_readlane broadcast (no LDS reads in
// the loop); per-point 64-lane min via HALVING multi-reduce (16 points share
// 4+2 shfl steps = ~1.1 shfl/point vs 6 for plain butterfly).
// ---------------------------------------------------------------------------
__global__ __launch_bounds__(256, 3) void fused_kernel(
    const float* __restrict__ xs,
    const float* __restrict__ pm,
    const float* __restrict__ em,
    const int*   __restrict__ faces,
    float* __restrict__ ws)
{
    __shared__ float redv[256];
    __shared__ float redc[4];

    const int bid  = blockIdx.x;
    const int tid  = threadIdx.x;
    const int lane = tid & 63;
    const int w    = tid >> 6;

    // ---------------- volume slice (regs die before edge table loads) ------
    {
        const int vb   = bid / BPB;
        const int j    = bid % BPB;
        const int fs   = (j * NF) / BPB;
        const int fcnt = (((j + 1) * NF) / BPB) - fs;   // 42 or 43
        float fvol = 0.0f;
        if (tid < fcnt) {
            const int* fp = faces + (size_t)(vb * NF + fs + tid) * 3;
            int i0 = fp[0], i1 = fp[1], i2 = fp[2];
            const float* p0 = xs + (size_t)(vb * NV + i0) * 3;
            const float* p1 = xs + (size_t)(vb * NV + i1) * 3;
            const float* p2 = xs + (size_t)(vb * NV + i2) * 3;
            float a0 = p0[0], a1 = p0[1], a2 = p0[2];
            float b0 = p1[0], b1 = p1[1], b2 = p1[2];
            float c0 = p2[0], c1 = p2[1], c2 = p2[2];
            float crx = a1 * b2 - a2 * b1;
            float cry = a2 * b0 - a0 * b2;
            float crz = a0 * b1 - a1 * b0;
            fvol = (crx * c0 + cry * c1 + crz * c2) * (1.0f / 6.0f);
        }
        redv[tid] = fvol;
    }

    // ---------------- chamfer: per-lane point projection --------------------
    const int chunk = bid & 31;
    const int pp    = bid >> 5;            // b*NP + p
    const int p     = pp % NP;
    const int b     = pp / NP;

    float vX, vY, x2v;
    {
        int v = chunk * 128 + w * 32 + (lane & 31);   // lanes 32-63 duplicate
        const float* x3 = xs + (size_t)(b * NV + v) * 3;
        float x = x3[0], y = x3[1], z = x3[2];
        const float* M = pm + p * 12;                 // uniform -> s_load
        float px = fmaf(M[0], x, fmaf(M[1], y, fmaf(M[2],  z, M[3])));
        float py = fmaf(M[4], x, fmaf(M[5], y, fmaf(M[6],  z, M[7])));
        float pz = fmaf(M[8], x, fmaf(M[9], y, fmaf(M[10], z, M[11])));
        float inv = 1.0f / pz;
        vX = px * inv;
        vY = py * inv;
        x2v = fmaf(vX, vX, vY * vY);
    }

    // Edge table into registers: lane holds 32 of the 2048 edges.
    const float4* em4 = (const float4*)em + (size_t)pp * (NE / 2);
    float ax[32], ay[32], cc[32];
#pragma unroll
    for (int k = 0; k < 16; ++k) {
        float4 e = em4[k * 64 + lane];
        ax[2 * k]     = -2.0f * e.x;
        ay[2 * k]     = -2.0f * e.y;
        cc[2 * k]     = fmaf(e.x, e.x, e.y * e.y);
        ax[2 * k + 1] = -2.0f * e.z;
        ay[2 * k + 1] = -2.0f * e.w;
        cc[2 * k + 1] = fmaf(e.z, e.z, e.w * e.w);
    }

    // ---------------- inner loop: 2 batches of 16 points --------------------
    // After each batch's halving reduce, lane holds point (lane&15) of the
    // batch fully min-reduced (x4 lane duplication).
    float msum = 0.0f;
#pragma unroll
    for (int B = 0; B < 2; ++B) {
        float mm[16];
#pragma unroll
        for (int q = 0; q < 16; ++q) {
            const int qq = B * 16 + q;
            float X = readlane_f(vX, qq);   // SGPR broadcast, no DS
            float Y = readlane_f(vY, qq);

            float t0 = fmaf(ay[0], Y, fmaf(ax[0], X, cc[0]));
            float t1 = fmaf(ay[1], Y, fmaf(ax[1], X, cc[1]));
            float m0 = fminf(t0, t1);
            t0 = fmaf(ay[2], Y, fmaf(ax[2], X, cc[2]));
            t1 = fmaf(ay[3], Y, fmaf(ax[3], X, cc[3]));
            float m1 = fminf(t0, t1);
            t0 = fmaf(ay[4], Y, fmaf(ax[4], X, cc[4]));
            t1 = fmaf(ay[5], Y, fmaf(ax[5], X, cc[5]));
            float m2 = fminf(t0, t1);
            t0 = fmaf(ay[6], Y, fmaf(ax[6], X, cc[6]));
            t1 = fmaf(ay[7], Y, fmaf(ax[7], X, cc[7]));
            float m3 = fminf(t0, t1);
#pragma unroll
            for (int k = 8; k < 32; k += 8) {
                t0 = fmaf(ay[k + 0], Y, fmaf(ax[k + 0], X, cc[k + 0]));
                t1 = fmaf(ay[k + 1], Y, fmaf(ax[k + 1], X, cc[k + 1]));
                m0 = fminf(fminf(m0, t0), t1);             // v_min3_f32
                t0 = fmaf(ay[k + 2], Y, fmaf(ax[k + 2], X, cc[k + 2]));
                t1 = fmaf(ay[k + 3], Y, fmaf(ax[k + 3], X, cc[k + 3]));
                m1 = fminf(fminf(m1, t0), t1);
                t0 = fmaf(ay[k + 4], Y, fmaf(ax[k + 4], X, cc[k + 4]));
                t1 = fmaf(ay[k + 5], Y, fmaf(ax[k + 5], X, cc[k + 5]));
                m2 = fminf(fminf(m2, t0), t1);
                t0 = fmaf(ay[k + 6], Y, fmaf(ax[k + 6], X, cc[k + 6]));
                t1 = fmaf(ay[k + 7], Y, fmaf(ax[k + 7], X, cc[k + 7]));
                m3 = fminf(fminf(m3, t0), t1);
            }
            mm[q] = fminf(fminf(m0, m1), fminf(m2, m3));
        }

        // Halving multi-reduce: step d keeps live/2 points, 1 shfl each.
        // Point identity after all steps: lane&15. Reduced over 16-lane group.
        {
            const bool b8 = (lane & 8) != 0;
#pragma unroll
            for (int j = 0; j < 8; ++j) {
                float keep = b8 ? mm[j + 8] : mm[j];
                float send = b8 ? mm[j] : mm[j + 8];
                mm[j] = fminf(keep, __shfl_xor(send, 8));
            }
            const bool b4 = (lane & 4) != 0;
#pragma unroll
            for (int j = 0; j < 4; ++j) {
                float keep = b4 ? mm[j + 4] : mm[j];
                float send = b4 ? mm[j] : mm[j + 4];
                mm[j] = fminf(keep, __shfl_xor(send, 4));
            }
            const bool b2 = (lane & 2) != 0;
#pragma unroll
            for (int j = 0; j < 2; ++j) {
                float keep = b2 ? mm[j + 2] : mm[j];
                float send = b2 ? mm[j] : mm[j + 2];
                mm[j] = fminf(keep, __shfl_xor(send, 2));
            }
            const bool b1 = (lane & 1) != 0;
            {
                float keep = b1 ? mm[1] : mm[0];
                float send = b1 ? mm[0] : mm[1];
                mm[0] = fminf(keep, __shfl_xor(send, 1));
            }
            // cross the four 16-lane groups (different edge quarters)
            mm[0] = fminf(mm[0], __shfl_xor(mm[0], 16));
            mm[0] = fminf(mm[0], __shfl_xor(mm[0], 32));
        }
        msum += mm[0];
    }

    // Per-lane msum covers point (lane&15) of both batches; each point is in
    // 4 lanes -> sum over lanes x0.25. x2v is in 2 lanes -> x0.5.
    float wsum;
    {
        float xsum = x2v;
        float ssum = msum;
#pragma unroll
        for (int off = 1; off < 64; off <<= 1) {
            xsum += __shfl_xor(xsum, off);
            ssum += __shfl_xor(ssum, off);
        }
        wsum = 0.25f * ssum + 0.5f * xsum;
    }

    // ---------------- block reductions -------------------------------------
    if (lane == 0) redc[w] = wsum;
    __syncthreads();
    for (int st = 128; st > 0; st >>= 1) {
        if (tid < st) redv[tid] += redv[tid + st];
        __syncthreads();
    }
    if (tid == 0) {
        ws[bid]        = (redc[0] + redc[1]) + (redc[2] + redc[3]);
        ws[NBLK + bid] = redv[0];
    }
}

// ---------------------------------------------------------------------------
// Finalize: 1 block, 256 threads; wave b handles batch b. Deterministic.
// ---------------------------------------------------------------------------
__global__ __launch_bounds__(256) void finalize_kernel(
    const float* __restrict__ ws,
    const float* __restrict__ tv,
    float* __restrict__ out)
{
    const int tid  = threadIdx.x;
    const int b    = tid >> 6;
    const int lane = tid & 63;

    const float* cp = ws + b * BPB + lane * 3;            // 192 chamfer partials
    const float* vp = ws + NBLK + b * BPB + lane * 3;     // 192 vol partials
    float cs = cp[0] + cp[1] + cp[2];
    float vs = vp[0] + vp[1] + vp[2];
#pragma unroll
    for (int off = 1; off < 64; off <<= 1) {
        cs += __shfl_xor(cs, off);
        vs += __shfl_xor(vs, off);
    }
    if (lane == 0) {
        out[b] = cs * (1.0f / (NP * NV));
        float d = fabsf(vs) - tv[b];
        out[4 + b] = d * d;
    }
}

// ---------------------------------------------------------------------------
extern "C" void kernel_launch(void* const* d_in, const int* in_sizes, int n_in,
                              void* d_out, int out_size, void* d_ws, size_t ws_size,
                              hipStream_t stream) {
    const float* xs    = (const float*)d_in[0];
    const float* pm    = (const float*)d_in[1];
    const float* em    = (const float*)d_in[2];
    const int*   faces = (const int*)d_in[3];
    const float* tv    = (const float*)d_in[4];
    float* out = (float*)d_out;
    float* ws  = (float*)d_ws;            // 1536 floats of partials

    fused_kernel<<<NBLK, 256, 0, stream>>>(xs, pm, em, faces, ws);
    finalize_kernel<<<1, 256, 0, stream>>>(ws, tv, out);
}

// Round 14
// 16.151 us; speedup vs baseline: 3.8403x; 1.4818x over previous
//
#include <hip/hip_runtime.h>

#define NB 4
#define NV 4096
#define NF 8192
#define NP 6
#define NE 2048

#define NBLK 768          // 3 blocks/CU x 256 CU -> one execution round
#define BPB  (NBLK / NB)  // 192 vol slices per batch

typedef short bf16x8  __attribute__((ext_vector_type(8)));
typedef float f32x16  __attribute__((ext_vector_type(16)));

// round-to-nearest-even fp32 -> bf16 (as ushort)
__device__ __forceinline__ unsigned short bf16_rn(float x) {
    unsigned int u = __float_as_uint(x);
    u = (u + 0x7FFFu + ((u >> 16) & 1u)) >> 16;
    return (unsigned short)u;
}
__device__ __forceinline__ float bf16f(unsigned short h) {
    return __uint_as_float(((unsigned int)h) << 16);
}

// ---------------------------------------------------------------------------
// MFMA chamfer: d2[e][v] = (x2+y2) + [ |e|^2 - 2(x*ex + y*ey) ].
// The bracket is a K=8 bf16 hi/lo split-precision dot (err ~2^-18 rel):
//   A[e] = {axh,axh,axl, ayh,ayh,ayl, cch,ccl}   (ax=-2ex, ay=-2ey, cc=|e|^2)
//   B[v] = {xh, xl, xh,  yh, yl, yh,  1,  1  }
// One mfma_f32_32x32x16_bf16 tile = 32 edges x 32 points (K slots 8..15 = 0).
// min over edges via per-lane fold of the 16 C regs + shfl_xor(32);
// x2 added after the min (exact: min(c)+s == min(c+s)).
// Block: 128 points x 2048 edges; wave w owns edges [w*512,(w+1)*512).
// ---------------------------------------------------------------------------
__global__ __launch_bounds__(256, 3) void fused_kernel(
    const float* __restrict__ xs,
    const float* __restrict__ pm,
    const float* __restrict__ em,
    const int*   __restrict__ faces,
    float* __restrict__ ws)
{
    __shared__ unsigned short Apack[NE][8];   // 32 KB
    __shared__ unsigned short Bpack[128][8];  // 2 KB
    __shared__ float x2s[128];
    __shared__ float pmin[4][128];
    __shared__ float redv[256];
    __shared__ float ch[128];

    const int bid  = blockIdx.x;
    const int tid  = threadIdx.x;
    const int lane = tid & 63;
    const int w    = tid >> 6;

    // ---------------- volume slice (unchanged champion code) ---------------
    {
        const int vb   = bid / BPB;
        const int j    = bid % BPB;
        const int fs   = (j * NF) / BPB;
        const int fcnt = (((j + 1) * NF) / BPB) - fs;   // 42 or 43
        float fvol = 0.0f;
        if (tid < fcnt) {
            const int* fp = faces + (size_t)(vb * NF + fs + tid) * 3;
            int i0 = fp[0], i1 = fp[1], i2 = fp[2];
            const float* p0 = xs + (size_t)(vb * NV + i0) * 3;
            const float* p1 = xs + (size_t)(vb * NV + i1) * 3;
            const float* p2 = xs + (size_t)(vb * NV + i2) * 3;
            float a0 = p0[0], a1 = p0[1], a2 = p0[2];
            float b0 = p1[0], b1 = p1[1], b2 = p1[2];
            float c0 = p2[0], c1 = p2[1], c2 = p2[2];
            float crx = a1 * b2 - a2 * b1;
            float cry = a2 * b0 - a0 * b2;
            float crz = a0 * b1 - a1 * b0;
            fvol = (crx * c0 + cry * c1 + crz * c2) * (1.0f / 6.0f);
        }
        redv[tid] = fvol;
    }

    const int chunk = bid & 31;
    const int pp    = bid >> 5;            // b*NP + p
    const int p     = pp % NP;
    const int b     = pp / NP;

    // ---------------- stage edges: 8 per thread, packed bf16 hi/lo ---------
    {
        const float2* e2 = (const float2*)em + (size_t)pp * NE;
#pragma unroll
        for (int i = 0; i < 8; ++i) {
            int ee = i * 256 + tid;
            float2 e = e2[ee];
            float ax = -2.0f * e.x, ay = -2.0f * e.y;
            float cc = fmaf(e.x, e.x, e.y * e.y);
            unsigned int axh = bf16_rn(ax);
            unsigned int axl = bf16_rn(ax - bf16f((unsigned short)axh));
            unsigned int ayh = bf16_rn(ay);
            unsigned int ayl = bf16_rn(ay - bf16f((unsigned short)ayh));
            unsigned int cch = bf16_rn(cc);
            unsigned int ccl = bf16_rn(cc - bf16f((unsigned short)cch));
            uint4 pk;
            pk.x = axh | (axh << 16);      // k0,k1
            pk.y = axl | (ayh << 16);      // k2,k3
            pk.z = ayh | (ayl << 16);      // k4,k5
            pk.w = cch | (ccl << 16);      // k6,k7
            *(uint4*)&Apack[ee][0] = pk;
        }
    }

    // ---------------- stage points: project + pack -------------------------
    if (tid < 128) {
        int v = chunk * 128 + tid;
        const float* x3 = xs + (size_t)(b * NV + v) * 3;
        float x = x3[0], y = x3[1], z = x3[2];
        const float* M = pm + p * 12;                  // uniform -> s_load
        float px = fmaf(M[0], x, fmaf(M[1], y, fmaf(M[2],  z, M[3])));
        float py = fmaf(M[4], x, fmaf(M[5], y, fmaf(M[6],  z, M[7])));
        float pz = fmaf(M[8], x, fmaf(M[9], y, fmaf(M[10], z, M[11])));
        float inv = 1.0f / pz;
        float X = px * inv, Y = py * inv;
        x2s[tid] = fmaf(X, X, Y * Y);
        unsigned int xh = bf16_rn(X);
        unsigned int xl = bf16_rn(X - bf16f((unsigned short)xh));
        unsigned int yh = bf16_rn(Y);
        unsigned int yl = bf16_rn(Y - bf16f((unsigned short)yh));
        uint4 pk;
        pk.x = xh | (xl << 16);            // k0,k1
        pk.y = xh | (yh << 16);            // k2,k3
        pk.z = yl | (yh << 16);            // k4,k5
        pk.w = 0x3F80u | (0x3F80u << 16);  // k6,k7 = 1.0, 1.0
        *(uint4*)&Bpack[tid][0] = pk;
    }
    __syncthreads();

    // ---------------- MFMA main loop ---------------------------------------
    const bf16x8 zfrag = {0, 0, 0, 0, 0, 0, 0, 0};
    const f32x16 zacc  = {0.f, 0.f, 0.f, 0.f, 0.f, 0.f, 0.f, 0.f,
                          0.f, 0.f, 0.f, 0.f, 0.f, 0.f, 0.f, 0.f};

    bf16x8 bfrag[4];
#pragma unroll
    for (int t = 0; t < 4; ++t)
        bfrag[t] = (lane < 32) ? *(const bf16x8*)&Bpack[t * 32 + lane][0] : zfrag;

    float rm[4] = {3.4e38f, 3.4e38f, 3.4e38f, 3.4e38f};

#pragma unroll 2
    for (int et = 0; et < 16; ++et) {
        bf16x8 afrag = (lane < 32)
                         ? *(const bf16x8*)&Apack[(w * 16 + et) * 32 + lane][0]
                         : zfrag;
#pragma unroll
        for (int t = 0; t < 4; ++t) {
            f32x16 c = __builtin_amdgcn_mfma_f32_32x32x16_bf16(afrag, bfrag[t], zacc, 0, 0, 0);
            float m = fminf(c[0], c[1]);
            m = fminf(fminf(m, c[2]),  c[3]);    // v_min3 chain
            m = fminf(fminf(m, c[4]),  c[5]);
            m = fminf(fminf(m, c[6]),  c[7]);
            m = fminf(fminf(m, c[8]),  c[9]);
            m = fminf(fminf(m, c[10]), c[11]);
            m = fminf(fminf(m, c[12]), c[13]);
            m = fminf(fminf(m, c[14]), c[15]);
            rm[t] = fminf(rm[t], m);
        }
    }

    // lane kg covers half the 32 rows; partner kg in lane^32
#pragma unroll
    for (int t = 0; t < 4; ++t)
        rm[t] = fminf(rm[t], __shfl_xor(rm[t], 32));
    if (lane < 32) {
#pragma unroll
        for (int t = 0; t < 4; ++t)
            pmin[w][t * 32 + lane] = rm[t];
    }
    __syncthreads();

    // ---------------- combine waves, add x^2, reduce ------------------------
    if (tid < 128) {
        float dm = fminf(fminf(pmin[0][tid], pmin[1][tid]),
                         fminf(pmin[2][tid], pmin[3][tid])) + x2s[tid];
        ch[tid] = dm;
    }
    __syncthreads();

    if (tid < 128) redv[tid] += redv[tid + 128];
    __syncthreads();
    for (int st = 64; st > 0; st >>= 1) {
        if (tid < st) {
            redv[tid] += redv[tid + st];
            ch[tid]   += ch[tid + st];
        }
        __syncthreads();
    }
    if (tid == 0) {
        ws[bid]        = ch[0];
        ws[NBLK + bid] = redv[0];
    }
}

// ---------------------------------------------------------------------------
// Finalize: 1 block, 256 threads; wave b handles batch b. Deterministic.
// ---------------------------------------------------------------------------
__global__ __launch_bounds__(256) void finalize_kernel(
    const float* __restrict__ ws,
    const float* __restrict__ tv,
    float* __restrict__ out)
{
    const int tid  = threadIdx.x;
    const int b    = tid >> 6;
    const int lane = tid & 63;

    const float* cp = ws + b * BPB + lane * 3;            // 192 chamfer partials
    const float* vp = ws + NBLK + b * BPB + lane * 3;     // 192 vol partials
    float cs = cp[0] + cp[1] + cp[2];
    float vs = vp[0] + vp[1] + vp[2];
#pragma unroll
    for (int off = 1; off < 64; off <<= 1) {
        cs += __shfl_xor(cs, off);
        vs += __shfl_xor(vs, off);
    }
    if (lane == 0) {
        out[b] = cs * (1.0f / (NP * NV));
        float d = fabsf(vs) - tv[b];
        out[4 + b] = d * d;
    }
}

// ---------------------------------------------------------------------------
extern "C" void kernel_launch(void* const* d_in, const int* in_sizes, int n_in,
                              void* d_out, int out_size, void* d_ws, size_t ws_size,
                              hipStream_t stream) {
    const float* xs    = (const float*)d_in[0];
    const float* pm    = (const float*)d_in[1];
    const float* em    = (const float*)d_in[2];
    const int*   faces = (const int*)d_in[3];
    const float* tv    = (const float*)d_in[4];
    float* out = (float*)d_out;
    float* ws  = (float*)d_ws;            // 1536 floats of partials

    fused_kernel<<<NBLK, 256, 0, stream>>>(xs, pm, em, faces, ws);
    finalize_kernel<<<1, 256, 0, stream>>>(ws, tv, out);
}